// Round 1
// baseline (787.115 us; speedup 1.0000x reference)
//
#include <hip/hip_runtime.h>
#include <hip/hip_bf16.h>

#define NROWS 8192
#define FD 256
#define NA 256
#define NH 16

typedef __attribute__((ext_vector_type(2))) float f32x2;
typedef __attribute__((ext_vector_type(4))) float f32x4;
typedef __attribute__((ext_vector_type(8))) __bf16 bf16x8;
typedef __attribute__((ext_vector_type(8))) unsigned short ushort8;

__device__ __forceinline__ unsigned short f2bf(float x) {
    unsigned int u = __builtin_bit_cast(unsigned int, x);
    u += 0x7FFFu + ((u >> 16) & 1u);
    return (unsigned short)(u >> 16);
}
__device__ __forceinline__ float bf2f(unsigned short b) {
    unsigned int u = ((unsigned int)b) << 16;
    return __builtin_bit_cast(float, u);
}

// ---------------- cvt kernels ----------------
__global__ __launch_bounds__(256) void cvt_x_kernel(const float* __restrict__ src,
                                                    unsigned short* __restrict__ dst) {
    size_t i = (size_t)blockIdx.x * 256 + threadIdx.x;   // 262144 threads, 8 elems each
    const f32x4* s = (const f32x4*)(src + i * 8);
    f32x4 a = s[0], b = s[1];
    ushort8 o;
    o[0] = f2bf(a.x); o[1] = f2bf(a.y); o[2] = f2bf(a.z); o[3] = f2bf(a.w);
    o[4] = f2bf(b.x); o[5] = f2bf(b.y); o[6] = f2bf(b.z); o[7] = f2bf(b.w);
    *(ushort8*)(dst + i * 8) = o;
}

__global__ __launch_bounds__(256) void cvt_w_kernel(const float* __restrict__ W1,
                                                    unsigned short* __restrict__ dst) {
    size_t i = (size_t)blockIdx.x * 256 + threadIdx.x;   // 131072 threads
    int k = ((int)i & 31) * 8;
    int f = ((int)(i >> 5)) & 255;
    int h = (int)(i >> 13);
    const float* s = W1 + ((size_t)(h * 256 + f)) * 512 + k;   // W1x part: c = k < 256
    const f32x4* s4 = (const f32x4*)s;
    f32x4 a = s4[0], b = s4[1];
    ushort8 o;
    o[0] = f2bf(a.x); o[1] = f2bf(a.y); o[2] = f2bf(a.z); o[3] = f2bf(a.w);
    o[4] = f2bf(b.x); o[5] = f2bf(b.y); o[6] = f2bf(b.z); o[7] = f2bf(b.w);
    *(ushort8*)(dst + i * 8) = o;
}

// ---------------- G = anchors @ W1a^T + b1 ----------------
__global__ __launch_bounds__(256) void g_kernel(const float* __restrict__ anchors,
                                                const float* __restrict__ W1,
                                                const float* __restrict__ b1,
                                                float* __restrict__ G) {
    __shared__ float anc_s[64][68];
    __shared__ float w_s[64][68];
    int h = blockIdx.x, a0 = blockIdx.y * 64, f0 = blockIdx.z * 64;
    int tid = threadIdx.x;
    int tf = tid & 15, av = tid >> 4;
    float acc[4][4] = {};   // [ia][jf]: a = a0+av+16*ia, f = f0+tf+16*jf
    int sr = tid >> 2, sc = (tid & 3) * 16;
    for (int kc = 0; kc < 4; ++kc) {
        int k0 = kc * 64;
        __syncthreads();
        {
            const float* s = anchors + (size_t)(a0 + sr) * FD + k0 + sc;
            const float* w = W1 + ((size_t)(h * 256 + f0 + sr)) * 512 + 256 + k0 + sc;
#pragma unroll
            for (int q = 0; q < 4; ++q) {
                *(f32x4*)&anc_s[sr][sc + q * 4] = *(const f32x4*)(s + q * 4);
                *(f32x4*)&w_s[sr][sc + q * 4]   = *(const f32x4*)(w + q * 4);
            }
        }
        __syncthreads();
#pragma unroll 8
        for (int k = 0; k < 64; ++k) {
            float avv[4], wvv[4];
#pragma unroll
            for (int ia = 0; ia < 4; ++ia) avv[ia] = anc_s[av + 16 * ia][k];
#pragma unroll
            for (int jf = 0; jf < 4; ++jf) wvv[jf] = w_s[tf + 16 * jf][k];
#pragma unroll
            for (int ia = 0; ia < 4; ++ia)
#pragma unroll
                for (int jf = 0; jf < 4; ++jf)
                    acc[ia][jf] = fmaf(avv[ia], wvv[jf], acc[ia][jf]);
        }
    }
#pragma unroll
    for (int ia = 0; ia < 4; ++ia) {
        int a = a0 + av + 16 * ia;
#pragma unroll
        for (int jf = 0; jf < 4; ++jf) {
            int f = f0 + tf + 16 * jf;
            G[((size_t)(h * 256 + a)) * FD + f] = acc[ia][jf] + b1[h * 256 + f];
        }
    }
}

// ---------------- HX = context @ W1x^T (bf16 MFMA) ----------------
__global__ __launch_bounds__(256) void hx_kernel(const unsigned short* __restrict__ Xb,
                                                 const unsigned short* __restrict__ Wb,
                                                 unsigned short* __restrict__ HXb,
                                                 int h0) {
    __shared__ unsigned short xs[128][40];
    __shared__ unsigned short ws2[128][40];
    int n0 = blockIdx.x * 128;
    int fg0 = blockIdx.y * 128;           // within h-group * 256
    int lh = fg0 >> 8;                    // local head
    int f0 = fg0 & 255;
    int h = h0 + lh;                      // global head
    int tid = threadIdx.x;
    int w = tid >> 6, lane = tid & 63;
    int wn = w & 1, wf = w >> 1;
    int arow = lane & 15, kg = lane >> 4;
    f32x4 acc[4][4] = {};
    int sr = tid >> 1, sc = (tid & 1) * 16;
    for (int kk = 0; kk < 8; ++kk) {
        int k0 = kk * 32;
        __syncthreads();
        {
            const ushort8* sx = (const ushort8*)(Xb + (size_t)(n0 + sr) * FD + k0 + sc);
            *(ushort8*)&xs[sr][sc]     = sx[0];
            *(ushort8*)&xs[sr][sc + 8] = sx[1];
            const ushort8* sw = (const ushort8*)(Wb + ((size_t)(h * 256 + f0 + sr)) * FD + k0 + sc);
            *(ushort8*)&ws2[sr][sc]     = sw[0];
            *(ushort8*)&ws2[sr][sc + 8] = sw[1];
        }
        __syncthreads();
        bf16x8 af[4], bfv[4];
#pragma unroll
        for (int i = 0; i < 4; ++i)
            af[i] = __builtin_bit_cast(bf16x8, *(const ushort8*)&xs[wn * 64 + i * 16 + arow][kg * 8]);
#pragma unroll
        for (int j = 0; j < 4; ++j)
            bfv[j] = __builtin_bit_cast(bf16x8, *(const ushort8*)&ws2[wf * 64 + j * 16 + arow][kg * 8]);
#pragma unroll
        for (int i = 0; i < 4; ++i)
#pragma unroll
            for (int j = 0; j < 4; ++j)
                acc[i][j] = __builtin_amdgcn_mfma_f32_16x16x32_bf16(af[i], bfv[j], acc[i][j], 0, 0, 0);
    }
    // C/D layout: col = lane&15, row = (lane>>4)*4 + r   [m89-verified]
#pragma unroll
    for (int i = 0; i < 4; ++i) {
        int nr = n0 + wn * 64 + i * 16 + kg * 4;
#pragma unroll
        for (int j = 0; j < 4; ++j) {
            int fc = f0 + wf * 64 + j * 16 + arow;
#pragma unroll
            for (int r = 0; r < 4; ++r)
                HXb[((size_t)lh * NROWS + nr + r) * FD + fc] = f2bf(acc[i][j][r]);
        }
    }
}

// ---------------- fused relu-dot + sigmoid + head-accumulate ----------------
__global__ __launch_bounds__(256, 1) void main_kernel(const unsigned short* __restrict__ HXb,
                                                      const float* __restrict__ G,
                                                      const float* __restrict__ W2,
                                                      const float* __restrict__ b2,
                                                      float* __restrict__ out,
                                                      int h0, int hcnt) {
    __shared__ float hxs[64][68];
    __shared__ float gs[128][68];
    int n0 = blockIdx.x * 64, a0 = blockIdx.y * 128;
    int tid = threadIdx.x;
    int tn = tid >> 4, ta = tid & 15;
    float att[4][8] = {};
    int hr = tid >> 2, hc = (tid & 3) * 16;   // hx stage: 64 rows x 64f, 16 bf16/thread
    int gr = tid >> 1, gc = (tid & 1) * 32;   // g stage: 128 rows x 64f, 32 f32/thread

    for (int lh = 0; lh < hcnt; ++lh) {
        int h = h0 + lh;
        f32x2 acc[4][8] = {};
        for (int fc4 = 0; fc4 < 4; ++fc4) {
            int f0 = fc4 * 64;
            __syncthreads();
            {   // stage hx chunk (bf16 -> f32)
                const ushort8* s = (const ushort8*)(HXb + ((size_t)lh * NROWS + n0 + hr) * FD + f0 + hc);
                ushort8 u0 = s[0], u1 = s[1];
                f32x4 t;
                t.x = bf2f(u0[0]); t.y = bf2f(u0[1]); t.z = bf2f(u0[2]); t.w = bf2f(u0[3]);
                *(f32x4*)&hxs[hr][hc] = t;
                t.x = bf2f(u0[4]); t.y = bf2f(u0[5]); t.z = bf2f(u0[6]); t.w = bf2f(u0[7]);
                *(f32x4*)&hxs[hr][hc + 4] = t;
                t.x = bf2f(u1[0]); t.y = bf2f(u1[1]); t.z = bf2f(u1[2]); t.w = bf2f(u1[3]);
                *(f32x4*)&hxs[hr][hc + 8] = t;
                t.x = bf2f(u1[4]); t.y = bf2f(u1[5]); t.z = bf2f(u1[6]); t.w = bf2f(u1[7]);
                *(f32x4*)&hxs[hr][hc + 12] = t;
            }
            {   // stage g chunk
                const float* s = G + ((size_t)h * NA + a0 + gr) * FD + f0 + gc;
#pragma unroll
                for (int q = 0; q < 8; ++q)
                    *(f32x4*)&gs[gr][gc + q * 4] = *(const f32x4*)(s + q * 4);
            }
            __syncthreads();
            const float* w2p = W2 + h * FD + f0;
#pragma unroll 4
            for (int f2 = 0; f2 < 32; ++f2) {
                f32x2 wv = *(const f32x2*)(w2p + f2 * 2);
                f32x2 hp[4], gp[8];
#pragma unroll
                for (int i = 0; i < 4; ++i) hp[i] = *(const f32x2*)&hxs[tn + 16 * i][f2 * 2];
#pragma unroll
                for (int j = 0; j < 8; ++j) gp[j] = *(const f32x2*)&gs[ta + 16 * j][f2 * 2];
#pragma unroll
                for (int i = 0; i < 4; ++i)
#pragma unroll
                    for (int j = 0; j < 8; ++j) {
                        f32x2 t = hp[i] + gp[j];
                        t = __builtin_elementwise_max(t, (f32x2)(0.0f));
                        acc[i][j] += t * wv;
                    }
            }
        }
        float bb = b2[h];
#pragma unroll
        for (int i = 0; i < 4; ++i)
#pragma unroll
            for (int j = 0; j < 8; ++j) {
                float s = acc[i][j].x + acc[i][j].y + bb;
                att[i][j] += 1.0f / (1.0f + __expf(-s));
            }
    }
#pragma unroll
    for (int i = 0; i < 4; ++i) {
        size_t n = n0 + tn + 16 * i;
#pragma unroll
        for (int j = 0; j < 8; ++j)
            out[n * NA + a0 + ta + 16 * j] += att[i][j] * (1.0f / 16.0f);
    }
}

extern "C" void kernel_launch(void* const* d_in, const int* in_sizes, int n_in,
                              void* d_out, int out_size, void* d_ws, size_t ws_size,
                              hipStream_t stream) {
    const float* ctx     = (const float*)d_in[0];
    const float* anchors = (const float*)d_in[1];
    const float* W1      = (const float*)d_in[2];
    const float* b1      = (const float*)d_in[3];
    const float* W2      = (const float*)d_in[4];
    const float* b2      = (const float*)d_in[5];
    float* out = (float*)d_out;
    char* ws = (char*)d_ws;

    const size_t SZ_G  = (size_t)NH * NA * FD * 4;        // 4 MiB
    const size_t SZ_XB = (size_t)NROWS * FD * 2;          // 4 MiB
    const size_t SZ_WB = (size_t)NH * FD * FD * 2;        // 2 MiB
    const size_t SZ_HX1 = (size_t)NROWS * FD * 2;         // 4 MiB per head
    const size_t fixed = SZ_G + SZ_XB + SZ_WB;

    int HG;
    if      (ws_size >= fixed + 16 * SZ_HX1) HG = 16;
    else if (ws_size >= fixed + 4 * SZ_HX1)  HG = 4;
    else if (ws_size >= fixed + 2 * SZ_HX1)  HG = 2;
    else                                      HG = 1;

    float* G            = (float*)(ws);
    unsigned short* Xb  = (unsigned short*)(ws + SZ_G);
    unsigned short* Wb  = (unsigned short*)(ws + SZ_G + SZ_XB);
    unsigned short* HXb = (unsigned short*)(ws + SZ_G + SZ_XB + SZ_WB);

    hipMemsetAsync(out, 0, (size_t)NROWS * NA * sizeof(float), stream);
    cvt_x_kernel<<<1024, 256, 0, stream>>>(ctx, Xb);
    cvt_w_kernel<<<512, 256, 0, stream>>>(W1, Wb);
    g_kernel<<<dim3(16, 4, 4), 256, 0, stream>>>(anchors, W1, b1, G);
    for (int h0 = 0; h0 < NH; h0 += HG) {
        hx_kernel<<<dim3(64, HG * 2), 256, 0, stream>>>(Xb, Wb, HXb, h0);
        main_kernel<<<dim3(128, 2), 256, 0, stream>>>(HXb, G, W2, b2, out, h0, HG);
    }
    hipMemcpyAsync(out + (size_t)NROWS * NA, anchors, (size_t)NA * FD * sizeof(float),
                   hipMemcpyDeviceToDevice, stream);
}

// Round 2
// 478.148 us; speedup vs baseline: 1.6462x; 1.6462x over previous
//
#include <hip/hip_runtime.h>
#include <hip/hip_bf16.h>

#define NROWS 8192
#define FD 256
#define NA 256
#define NH 16
#define FCH 64           // f-chunk staged in LDS per iteration
#define LDH 72           // padded LDS row stride (f16 units): 144 B -> 2-way max conflicts

typedef __attribute__((ext_vector_type(2))) float f32x2;
typedef __attribute__((ext_vector_type(4))) float f32x4;
typedef __attribute__((ext_vector_type(8))) __bf16 bf16x8;
typedef __attribute__((ext_vector_type(8))) unsigned short ushort8;
typedef __attribute__((ext_vector_type(2))) _Float16 h16x2;
typedef __attribute__((ext_vector_type(8))) _Float16 h16x8;

__device__ __forceinline__ unsigned short f2bf(float x) {
    unsigned int u = __builtin_bit_cast(unsigned int, x);
    u += 0x7FFFu + ((u >> 16) & 1u);
    return (unsigned short)(u >> 16);
}

// ---------------- cvt kernels (bf16 inputs for the MFMA GEMM) ----------------
__global__ __launch_bounds__(256) void cvt_x_kernel(const float* __restrict__ src,
                                                    unsigned short* __restrict__ dst) {
    size_t i = (size_t)blockIdx.x * 256 + threadIdx.x;   // 262144 threads, 8 elems each
    const f32x4* s = (const f32x4*)(src + i * 8);
    f32x4 a = s[0], b = s[1];
    ushort8 o;
    o[0] = f2bf(a.x); o[1] = f2bf(a.y); o[2] = f2bf(a.z); o[3] = f2bf(a.w);
    o[4] = f2bf(b.x); o[5] = f2bf(b.y); o[6] = f2bf(b.z); o[7] = f2bf(b.w);
    *(ushort8*)(dst + i * 8) = o;
}

__global__ __launch_bounds__(256) void cvt_w_kernel(const float* __restrict__ W1,
                                                    unsigned short* __restrict__ dst) {
    size_t i = (size_t)blockIdx.x * 256 + threadIdx.x;   // 131072 threads
    int k = ((int)i & 31) * 8;
    int f = ((int)(i >> 5)) & 255;
    int h = (int)(i >> 13);
    const float* s = W1 + ((size_t)(h * 256 + f)) * 512 + k;   // W1x part
    const f32x4* s4 = (const f32x4*)s;
    f32x4 a = s4[0], b = s4[1];
    ushort8 o;
    o[0] = f2bf(a.x); o[1] = f2bf(a.y); o[2] = f2bf(a.z); o[3] = f2bf(a.w);
    o[4] = f2bf(b.x); o[5] = f2bf(b.y); o[6] = f2bf(b.z); o[7] = f2bf(b.w);
    *(ushort8*)(dst + i * 8) = o;
}

__global__ __launch_bounds__(256) void cvt_w2_kernel(const float* __restrict__ W2,
                                                     _Float16* __restrict__ W2h) {
    int i = blockIdx.x * 256 + threadIdx.x;              // 4096 total
    W2h[i] = (_Float16)W2[i];
}

// ---------------- G = anchors @ W1a^T + b1  (f16 output) ----------------
__global__ __launch_bounds__(256) void g_kernel(const float* __restrict__ anchors,
                                                const float* __restrict__ W1,
                                                const float* __restrict__ b1,
                                                _Float16* __restrict__ Gh) {
    __shared__ float anc_s[64][68];
    __shared__ float w_s[64][68];
    int h = blockIdx.x, a0 = blockIdx.y * 64, f0 = blockIdx.z * 64;
    int tid = threadIdx.x;
    int tf = tid & 15, av = tid >> 4;
    float acc[4][4] = {};
    int sr = tid >> 2, sc = (tid & 3) * 16;
    for (int kc = 0; kc < 4; ++kc) {
        int k0 = kc * 64;
        __syncthreads();
        {
            const float* s = anchors + (size_t)(a0 + sr) * FD + k0 + sc;
            const float* w = W1 + ((size_t)(h * 256 + f0 + sr)) * 512 + 256 + k0 + sc;
#pragma unroll
            for (int q = 0; q < 4; ++q) {
                *(f32x4*)&anc_s[sr][sc + q * 4] = *(const f32x4*)(s + q * 4);
                *(f32x4*)&w_s[sr][sc + q * 4]   = *(const f32x4*)(w + q * 4);
            }
        }
        __syncthreads();
#pragma unroll 8
        for (int k = 0; k < 64; ++k) {
            float avv[4], wvv[4];
#pragma unroll
            for (int ia = 0; ia < 4; ++ia) avv[ia] = anc_s[av + 16 * ia][k];
#pragma unroll
            for (int jf = 0; jf < 4; ++jf) wvv[jf] = w_s[tf + 16 * jf][k];
#pragma unroll
            for (int ia = 0; ia < 4; ++ia)
#pragma unroll
                for (int jf = 0; jf < 4; ++jf)
                    acc[ia][jf] = fmaf(avv[ia], wvv[jf], acc[ia][jf]);
        }
    }
#pragma unroll
    for (int ia = 0; ia < 4; ++ia) {
        int a = a0 + av + 16 * ia;
#pragma unroll
        for (int jf = 0; jf < 4; ++jf) {
            int f = f0 + tf + 16 * jf;
            Gh[((size_t)(h * 256 + a)) * FD + f] = (_Float16)(acc[ia][jf] + b1[h * 256 + f]);
        }
    }
}

// ---------------- HX = context @ W1x^T (bf16 MFMA, f16 output) ----------------
__global__ __launch_bounds__(256) void hx_kernel(const unsigned short* __restrict__ Xb,
                                                 const unsigned short* __restrict__ Wb,
                                                 _Float16* __restrict__ HXh,
                                                 int h0) {
    __shared__ unsigned short xs[128][40];
    __shared__ unsigned short ws2[128][40];
    int n0 = blockIdx.x * 128;
    int fg0 = blockIdx.y * 128;           // within h-group * 256
    int lh = fg0 >> 8;                    // local (buffer) head
    int f0 = fg0 & 255;
    int h = h0 + lh;                      // global head
    int tid = threadIdx.x;
    int w = tid >> 6, lane = tid & 63;
    int wn = w & 1, wf = w >> 1;
    int arow = lane & 15, kg = lane >> 4;
    f32x4 acc[4][4] = {};
    int sr = tid >> 1, sc = (tid & 1) * 16;
    for (int kk = 0; kk < 8; ++kk) {
        int k0 = kk * 32;
        __syncthreads();
        {
            const ushort8* sx = (const ushort8*)(Xb + (size_t)(n0 + sr) * FD + k0 + sc);
            *(ushort8*)&xs[sr][sc]     = sx[0];
            *(ushort8*)&xs[sr][sc + 8] = sx[1];
            const ushort8* sw = (const ushort8*)(Wb + ((size_t)(h * 256 + f0 + sr)) * FD + k0 + sc);
            *(ushort8*)&ws2[sr][sc]     = sw[0];
            *(ushort8*)&ws2[sr][sc + 8] = sw[1];
        }
        __syncthreads();
        bf16x8 af[4], bfv[4];
#pragma unroll
        for (int i = 0; i < 4; ++i)
            af[i] = __builtin_bit_cast(bf16x8, *(const ushort8*)&xs[wn * 64 + i * 16 + arow][kg * 8]);
#pragma unroll
        for (int j = 0; j < 4; ++j)
            bfv[j] = __builtin_bit_cast(bf16x8, *(const ushort8*)&ws2[wf * 64 + j * 16 + arow][kg * 8]);
#pragma unroll
        for (int i = 0; i < 4; ++i)
#pragma unroll
            for (int j = 0; j < 4; ++j)
                acc[i][j] = __builtin_amdgcn_mfma_f32_16x16x32_bf16(af[i], bfv[j], acc[i][j], 0, 0, 0);
    }
    // C/D layout: col = lane&15, row = (lane>>4)*4 + r   [m89-verified]
#pragma unroll
    for (int i = 0; i < 4; ++i) {
        int nr = n0 + wn * 64 + i * 16 + kg * 4;
#pragma unroll
        for (int j = 0; j < 4; ++j) {
            int fc = f0 + wf * 64 + j * 16 + arow;
#pragma unroll
            for (int r = 0; r < 4; ++r)
                HXh[((size_t)lh * NROWS + nr + r) * FD + fc] = (_Float16)acc[i][j][r];
        }
    }
}

// ---------------- fused relu-dot + sigmoid + head-accumulate (packed f16) ----------------
__global__ __launch_bounds__(256, 3) void main2_kernel(const _Float16* __restrict__ HXh,
                                                       const _Float16* __restrict__ Gh,
                                                       const _Float16* __restrict__ W2h,
                                                       const float* __restrict__ b2,
                                                       float* __restrict__ out,
                                                       int h0, int hpb) {
    __shared__ _Float16 hxs[64][LDH];
    __shared__ _Float16 gs[128][LDH];
    __shared__ __align__(16) _Float16 w2s[FCH];
    int n0 = blockIdx.x * 64, a0 = blockIdx.y * 128;
    int hb = blockIdx.z * hpb;            // buffer-head base
    int tid = threadIdx.x;
    int tn = tid >> 4, ta = tid & 15;
    float att[4][8] = {};
    int hr = tid >> 2, hc = (tid & 3) * 16;   // hxs staging: 16 f16/thread
    int gr = tid >> 1, gc = (tid & 1) * 32;   // gs staging:  32 f16/thread

    const h16x2 zero2 = {(_Float16)0.0f, (_Float16)0.0f};

#pragma unroll 1
    for (int lh = 0; lh < hpb; ++lh) {
        int bufh = hb + lh;               // index into HXh
        int h = h0 + bufh;                // global head
        float acc[4][8] = {};
#pragma unroll 1
        for (int fc = 0; fc < FD; fc += FCH) {
            __syncthreads();
            {   // stage hx chunk (f16, b128 writes)
                const _Float16* s = HXh + ((size_t)bufh * NROWS + n0 + hr) * FD + fc + hc;
                *(h16x8*)&hxs[hr][hc]     = *(const h16x8*)(s);
                *(h16x8*)&hxs[hr][hc + 8] = *(const h16x8*)(s + 8);
            }
            {   // stage g chunk
                const _Float16* s = Gh + ((size_t)h * NA + a0 + gr) * FD + fc + gc;
#pragma unroll
                for (int q = 0; q < 4; ++q)
                    *(h16x8*)&gs[gr][gc + q * 8] = *(const h16x8*)(s + q * 8);
            }
            if (tid < FCH / 8)   // stage w2 chunk (128 B)
                *(h16x8*)&w2s[tid * 8] = *(const h16x8*)(W2h + h * FD + fc + tid * 8);
            __syncthreads();
#pragma unroll
            for (int g8 = 0; g8 < FCH / 8; ++g8) {
                h16x8 wv = *(const h16x8*)&w2s[g8 * 8];
                h16x8 hv[4], gv[8];
#pragma unroll
                for (int i = 0; i < 4; ++i)
                    hv[i] = *(const h16x8*)&hxs[tn + 16 * i][g8 * 8];
#pragma unroll
                for (int j = 0; j < 8; ++j)
                    gv[j] = *(const h16x8*)&gs[ta + 16 * j][g8 * 8];
#pragma unroll
                for (int q = 0; q < 4; ++q) {
                    h16x2 wq; wq[0] = wv[2 * q]; wq[1] = wv[2 * q + 1];
                    h16x2 hq[4], gq[8];
#pragma unroll
                    for (int i = 0; i < 4; ++i) { hq[i][0] = hv[i][2 * q]; hq[i][1] = hv[i][2 * q + 1]; }
#pragma unroll
                    for (int j = 0; j < 8; ++j) { gq[j][0] = gv[j][2 * q]; gq[j][1] = gv[j][2 * q + 1]; }
#pragma unroll
                    for (int i = 0; i < 4; ++i)
#pragma unroll
                        for (int j = 0; j < 8; ++j) {
                            h16x2 t = hq[i] + gq[j];              // v_pk_add_f16
                            t = __builtin_elementwise_max(t, zero2); // v_pk_max_f16
                            acc[i][j] = __builtin_amdgcn_fdot2(t, wq, acc[i][j], false); // v_dot2
                        }
                }
            }
        }
        float bb = b2[h];
#pragma unroll
        for (int i = 0; i < 4; ++i)
#pragma unroll
            for (int j = 0; j < 8; ++j) {
                float s = acc[i][j] + bb;
                att[i][j] += 1.0f / (1.0f + __expf(-s));
            }
    }
#pragma unroll
    for (int i = 0; i < 4; ++i) {
        size_t n = n0 + tn + 16 * i;
#pragma unroll
        for (int j = 0; j < 8; ++j)
            atomicAdd(&out[n * NA + a0 + ta + 16 * j], att[i][j] * (1.0f / 16.0f));
    }
}

extern "C" void kernel_launch(void* const* d_in, const int* in_sizes, int n_in,
                              void* d_out, int out_size, void* d_ws, size_t ws_size,
                              hipStream_t stream) {
    const float* ctx     = (const float*)d_in[0];
    const float* anchors = (const float*)d_in[1];
    const float* W1      = (const float*)d_in[2];
    const float* b1      = (const float*)d_in[3];
    const float* W2      = (const float*)d_in[4];
    const float* b2      = (const float*)d_in[5];
    float* out = (float*)d_out;
    char* ws = (char*)d_ws;

    const size_t SZ_G   = (size_t)NH * NA * FD * 2;       // 2 MiB (f16)
    const size_t SZ_XB  = (size_t)NROWS * FD * 2;         // 4 MiB (bf16)
    const size_t SZ_WB  = (size_t)NH * FD * FD * 2;       // 2 MiB (bf16)
    const size_t SZ_W2  = (size_t)NH * FD * 2;            // 8 KiB (f16)
    const size_t SZ_HX1 = (size_t)NROWS * FD * 2;         // 4 MiB per head (f16)
    const size_t fixed = SZ_G + SZ_XB + SZ_WB + SZ_W2;

    int HG;
    if      (ws_size >= fixed + 16 * SZ_HX1) HG = 16;
    else if (ws_size >= fixed + 4 * SZ_HX1)  HG = 4;
    else if (ws_size >= fixed + 2 * SZ_HX1)  HG = 2;
    else                                      HG = 1;

    _Float16* Gh       = (_Float16*)(ws);
    unsigned short* Xb = (unsigned short*)(ws + SZ_G);
    unsigned short* Wb = (unsigned short*)(ws + SZ_G + SZ_XB);
    _Float16* W2h      = (_Float16*)(ws + SZ_G + SZ_XB + SZ_WB);
    _Float16* HXh      = (_Float16*)(ws + SZ_G + SZ_XB + SZ_WB + SZ_W2);

    hipMemsetAsync(out, 0, (size_t)NROWS * NA * sizeof(float), stream);
    cvt_x_kernel<<<1024, 256, 0, stream>>>(ctx, Xb);
    cvt_w_kernel<<<512, 256, 0, stream>>>(W1, Wb);
    cvt_w2_kernel<<<16, 256, 0, stream>>>(W2, W2h);
    g_kernel<<<dim3(16, 4, 4), 256, 0, stream>>>(anchors, W1, b1, Gh);

    int hpb = (HG >= 4) ? 4 : HG;         // heads per main-block
    for (int h0 = 0; h0 < NH; h0 += HG) {
        hx_kernel<<<dim3(64, HG * 2), 256, 0, stream>>>(Xb, Wb, HXh, h0);
        main2_kernel<<<dim3(128, 2, HG / hpb), 256, 0, stream>>>(HXh, Gh, W2h, b2, out, h0, hpb);
    }
    hipMemcpyAsync(out + (size_t)NROWS * NA, anchors, (size_t)NA * FD * sizeof(float),
                   hipMemcpyDeviceToDevice, stream);
}

// Round 3
// 456.385 us; speedup vs baseline: 1.7247x; 1.0477x over previous
//
#include <hip/hip_runtime.h>
#include <hip/hip_bf16.h>

#define NROWS 8192
#define FD 256
#define NA 256
#define NH 16
#define FCH 64           // f-chunk staged in LDS per iteration
#define LDH 72           // padded LDS row stride (f16 units): 144 B -> 2-way max conflicts

typedef __attribute__((ext_vector_type(2))) float f32x2;
typedef __attribute__((ext_vector_type(4))) float f32x4;
typedef __attribute__((ext_vector_type(8))) __bf16 bf16x8;
typedef __attribute__((ext_vector_type(8))) unsigned short ushort8;
typedef __attribute__((ext_vector_type(2))) _Float16 h16x2;
typedef __attribute__((ext_vector_type(8))) _Float16 h16x8;

struct h2q { h16x2 p[4]; };   // view of one h16x8 (4 VGPRs) as 4 packed pairs

__device__ __forceinline__ unsigned short f2bf(float x) {
    unsigned int u = __builtin_bit_cast(unsigned int, x);
    u += 0x7FFFu + ((u >> 16) & 1u);
    return (unsigned short)(u >> 16);
}

// relu(h+g) dot w2 accumulated into acc: exactly 3 VALU insts, forced packed.
__device__ __forceinline__ float relu_dot2(h16x2 h, h16x2 g, h16x2 w, float acc) {
    h16x2 t;
    asm("v_pk_add_f16 %0, %1, %2\n\t"
        "v_pk_max_f16 %0, %0, 0"
        : "=v"(t) : "v"(h), "v"(g));
    return __builtin_amdgcn_fdot2(t, w, acc, false);
}

// ---------------- cvt kernels (bf16 inputs for the MFMA GEMM) ----------------
__global__ __launch_bounds__(256) void cvt_x_kernel(const float* __restrict__ src,
                                                    unsigned short* __restrict__ dst) {
    size_t i = (size_t)blockIdx.x * 256 + threadIdx.x;   // 262144 threads, 8 elems each
    const f32x4* s = (const f32x4*)(src + i * 8);
    f32x4 a = s[0], b = s[1];
    ushort8 o;
    o[0] = f2bf(a.x); o[1] = f2bf(a.y); o[2] = f2bf(a.z); o[3] = f2bf(a.w);
    o[4] = f2bf(b.x); o[5] = f2bf(b.y); o[6] = f2bf(b.z); o[7] = f2bf(b.w);
    *(ushort8*)(dst + i * 8) = o;
}

__global__ __launch_bounds__(256) void cvt_w_kernel(const float* __restrict__ W1,
                                                    unsigned short* __restrict__ dst) {
    size_t i = (size_t)blockIdx.x * 256 + threadIdx.x;   // 131072 threads
    int k = ((int)i & 31) * 8;
    int f = ((int)(i >> 5)) & 255;
    int h = (int)(i >> 13);
    const float* s = W1 + ((size_t)(h * 256 + f)) * 512 + k;   // W1x part
    const f32x4* s4 = (const f32x4*)s;
    f32x4 a = s4[0], b = s4[1];
    ushort8 o;
    o[0] = f2bf(a.x); o[1] = f2bf(a.y); o[2] = f2bf(a.z); o[3] = f2bf(a.w);
    o[4] = f2bf(b.x); o[5] = f2bf(b.y); o[6] = f2bf(b.z); o[7] = f2bf(b.w);
    *(ushort8*)(dst + i * 8) = o;
}

__global__ __launch_bounds__(256) void cvt_w2_kernel(const float* __restrict__ W2,
                                                     _Float16* __restrict__ W2h) {
    int i = blockIdx.x * 256 + threadIdx.x;              // 4096 total
    W2h[i] = (_Float16)W2[i];
}

// ---------------- G = anchors @ W1a^T + b1  (f16 output) ----------------
__global__ __launch_bounds__(256) void g_kernel(const float* __restrict__ anchors,
                                                const float* __restrict__ W1,
                                                const float* __restrict__ b1,
                                                _Float16* __restrict__ Gh) {
    __shared__ float anc_s[64][68];
    __shared__ float w_s[64][68];
    int h = blockIdx.x, a0 = blockIdx.y * 64, f0 = blockIdx.z * 64;
    int tid = threadIdx.x;
    int tf = tid & 15, av = tid >> 4;
    float acc[4][4] = {};
    int sr = tid >> 2, sc = (tid & 3) * 16;
    for (int kc = 0; kc < 4; ++kc) {
        int k0 = kc * 64;
        __syncthreads();
        {
            const float* s = anchors + (size_t)(a0 + sr) * FD + k0 + sc;
            const float* w = W1 + ((size_t)(h * 256 + f0 + sr)) * 512 + 256 + k0 + sc;
#pragma unroll
            for (int q = 0; q < 4; ++q) {
                *(f32x4*)&anc_s[sr][sc + q * 4] = *(const f32x4*)(s + q * 4);
                *(f32x4*)&w_s[sr][sc + q * 4]   = *(const f32x4*)(w + q * 4);
            }
        }
        __syncthreads();
#pragma unroll 8
        for (int k = 0; k < 64; ++k) {
            float avv[4], wvv[4];
#pragma unroll
            for (int ia = 0; ia < 4; ++ia) avv[ia] = anc_s[av + 16 * ia][k];
#pragma unroll
            for (int jf = 0; jf < 4; ++jf) wvv[jf] = w_s[tf + 16 * jf][k];
#pragma unroll
            for (int ia = 0; ia < 4; ++ia)
#pragma unroll
                for (int jf = 0; jf < 4; ++jf)
                    acc[ia][jf] = fmaf(avv[ia], wvv[jf], acc[ia][jf]);
        }
    }
#pragma unroll
    for (int ia = 0; ia < 4; ++ia) {
        int a = a0 + av + 16 * ia;
#pragma unroll
        for (int jf = 0; jf < 4; ++jf) {
            int f = f0 + tf + 16 * jf;
            Gh[((size_t)(h * 256 + a)) * FD + f] = (_Float16)(acc[ia][jf] + b1[h * 256 + f]);
        }
    }
}

// ---------------- HX = context @ W1x^T (bf16 MFMA, f16 output) ----------------
__global__ __launch_bounds__(256) void hx_kernel(const unsigned short* __restrict__ Xb,
                                                 const unsigned short* __restrict__ Wb,
                                                 _Float16* __restrict__ HXh,
                                                 int h0) {
    __shared__ unsigned short xs[128][40];
    __shared__ unsigned short ws2[128][40];
    int n0 = blockIdx.x * 128;
    int fg0 = blockIdx.y * 128;           // within h-group * 256
    int lh = fg0 >> 8;                    // local (buffer) head
    int f0 = fg0 & 255;
    int h = h0 + lh;                      // global head
    int tid = threadIdx.x;
    int w = tid >> 6, lane = tid & 63;
    int wn = w & 1, wf = w >> 1;
    int arow = lane & 15, kg = lane >> 4;
    f32x4 acc[4][4] = {};
    int sr = tid >> 1, sc = (tid & 1) * 16;
    for (int kk = 0; kk < 8; ++kk) {
        int k0 = kk * 32;
        __syncthreads();
        {
            const ushort8* sx = (const ushort8*)(Xb + (size_t)(n0 + sr) * FD + k0 + sc);
            *(ushort8*)&xs[sr][sc]     = sx[0];
            *(ushort8*)&xs[sr][sc + 8] = sx[1];
            const ushort8* sw = (const ushort8*)(Wb + ((size_t)(h * 256 + f0 + sr)) * FD + k0 + sc);
            *(ushort8*)&ws2[sr][sc]     = sw[0];
            *(ushort8*)&ws2[sr][sc + 8] = sw[1];
        }
        __syncthreads();
        bf16x8 af[4], bfv[4];
#pragma unroll
        for (int i = 0; i < 4; ++i)
            af[i] = __builtin_bit_cast(bf16x8, *(const ushort8*)&xs[wn * 64 + i * 16 + arow][kg * 8]);
#pragma unroll
        for (int j = 0; j < 4; ++j)
            bfv[j] = __builtin_bit_cast(bf16x8, *(const ushort8*)&ws2[wf * 64 + j * 16 + arow][kg * 8]);
#pragma unroll
        for (int i = 0; i < 4; ++i)
#pragma unroll
            for (int j = 0; j < 4; ++j)
                acc[i][j] = __builtin_amdgcn_mfma_f32_16x16x32_bf16(af[i], bfv[j], acc[i][j], 0, 0, 0);
    }
    // C/D layout: col = lane&15, row = (lane>>4)*4 + r   [m89-verified]
#pragma unroll
    for (int i = 0; i < 4; ++i) {
        int nr = n0 + wn * 64 + i * 16 + kg * 4;
#pragma unroll
        for (int j = 0; j < 4; ++j) {
            int fc = f0 + wf * 64 + j * 16 + arow;
#pragma unroll
            for (int r = 0; r < 4; ++r)
                HXh[((size_t)lh * NROWS + nr + r) * FD + fc] = (_Float16)acc[i][j][r];
        }
    }
}

// ---------------- fused relu-dot + sigmoid + head-accumulate (packed f16) ----------------
__global__ __launch_bounds__(256, 4) void main2_kernel(const _Float16* __restrict__ HXh,
                                                       const _Float16* __restrict__ Gh,
                                                       const _Float16* __restrict__ W2h,
                                                       const float* __restrict__ b2,
                                                       float* __restrict__ out,
                                                       int h0, int hpb) {
    __shared__ _Float16 hxs[64][LDH];
    __shared__ _Float16 gs[128][LDH];
    __shared__ __align__(16) _Float16 w2s[FCH];
    int n0 = blockIdx.x * 64, a0 = blockIdx.y * 128;
    int hb = blockIdx.z * hpb;            // buffer-head base
    int tid = threadIdx.x;
    int tn = tid >> 4, ta = tid & 15;
    float att[4][8] = {};
    int hr = tid >> 2, hc = (tid & 3) * 16;   // hxs staging: 16 f16/thread
    int gr = tid >> 1, gc = (tid & 1) * 32;   // gs staging:  32 f16/thread

#pragma unroll 1
    for (int lh = 0; lh < hpb; ++lh) {
        int bufh = hb + lh;               // index into HXh
        int h = h0 + bufh;                // global head
        float acc[4][8] = {};
#pragma unroll 1
        for (int fc = 0; fc < FD; fc += FCH) {
            __syncthreads();
            {   // stage hx chunk (f16, b128 writes)
                const _Float16* s = HXh + ((size_t)bufh * NROWS + n0 + hr) * FD + fc + hc;
                *(h16x8*)&hxs[hr][hc]     = *(const h16x8*)(s);
                *(h16x8*)&hxs[hr][hc + 8] = *(const h16x8*)(s + 8);
            }
            {   // stage g chunk
                const _Float16* s = Gh + ((size_t)h * NA + a0 + gr) * FD + fc + gc;
#pragma unroll
                for (int q = 0; q < 4; ++q)
                    *(h16x8*)&gs[gr][gc + q * 8] = *(const h16x8*)(s + q * 8);
            }
            if (tid < FCH / 8)   // stage w2 chunk (128 B)
                *(h16x8*)&w2s[tid * 8] = *(const h16x8*)(W2h + h * FD + fc + tid * 8);
            __syncthreads();
#pragma unroll
            for (int g8 = 0; g8 < FCH / 8; ++g8) {
                h2q wq = __builtin_bit_cast(h2q, *(const h16x8*)&w2s[g8 * 8]);
                h2q hq[4], gq[8];
#pragma unroll
                for (int i = 0; i < 4; ++i)
                    hq[i] = __builtin_bit_cast(h2q, *(const h16x8*)&hxs[tn + 16 * i][g8 * 8]);
#pragma unroll
                for (int j = 0; j < 8; ++j)
                    gq[j] = __builtin_bit_cast(h2q, *(const h16x8*)&gs[ta + 16 * j][g8 * 8]);
#pragma unroll
                for (int q = 0; q < 4; ++q)
#pragma unroll
                    for (int i = 0; i < 4; ++i)
#pragma unroll
                        for (int j = 0; j < 8; ++j)
                            acc[i][j] = relu_dot2(hq[i].p[q], gq[j].p[q], wq.p[q], acc[i][j]);
            }
        }
        float bb = b2[h];
#pragma unroll
        for (int i = 0; i < 4; ++i)
#pragma unroll
            for (int j = 0; j < 8; ++j) {
                float s = acc[i][j] + bb;
                att[i][j] += 1.0f / (1.0f + __expf(-s));
            }
    }
#pragma unroll
    for (int i = 0; i < 4; ++i) {
        size_t n = n0 + tn + 16 * i;
#pragma unroll
        for (int j = 0; j < 8; ++j)
            atomicAdd(&out[n * NA + a0 + ta + 16 * j], att[i][j] * (1.0f / 16.0f));
    }
}

extern "C" void kernel_launch(void* const* d_in, const int* in_sizes, int n_in,
                              void* d_out, int out_size, void* d_ws, size_t ws_size,
                              hipStream_t stream) {
    const float* ctx     = (const float*)d_in[0];
    const float* anchors = (const float*)d_in[1];
    const float* W1      = (const float*)d_in[2];
    const float* b1      = (const float*)d_in[3];
    const float* W2      = (const float*)d_in[4];
    const float* b2      = (const float*)d_in[5];
    float* out = (float*)d_out;
    char* ws = (char*)d_ws;

    const size_t SZ_G   = (size_t)NH * NA * FD * 2;       // 2 MiB (f16)
    const size_t SZ_XB  = (size_t)NROWS * FD * 2;         // 4 MiB (bf16)
    const size_t SZ_WB  = (size_t)NH * FD * FD * 2;       // 2 MiB (bf16)
    const size_t SZ_W2  = (size_t)NH * FD * 2;            // 8 KiB (f16)
    const size_t SZ_HX1 = (size_t)NROWS * FD * 2;         // 4 MiB per head (f16)
    const size_t fixed = SZ_G + SZ_XB + SZ_WB + SZ_W2;

    int HG;
    if      (ws_size >= fixed + 16 * SZ_HX1) HG = 16;
    else if (ws_size >= fixed + 4 * SZ_HX1)  HG = 4;
    else if (ws_size >= fixed + 2 * SZ_HX1)  HG = 2;
    else                                      HG = 1;

    _Float16* Gh       = (_Float16*)(ws);
    unsigned short* Xb = (unsigned short*)(ws + SZ_G);
    unsigned short* Wb = (unsigned short*)(ws + SZ_G + SZ_XB);
    _Float16* W2h      = (_Float16*)(ws + SZ_G + SZ_XB + SZ_WB);
    _Float16* HXh      = (_Float16*)(ws + SZ_G + SZ_XB + SZ_WB + SZ_W2);

    hipMemsetAsync(out, 0, (size_t)NROWS * NA * sizeof(float), stream);
    cvt_x_kernel<<<1024, 256, 0, stream>>>(ctx, Xb);
    cvt_w_kernel<<<512, 256, 0, stream>>>(W1, Wb);
    cvt_w2_kernel<<<16, 256, 0, stream>>>(W2, W2h);
    g_kernel<<<dim3(16, 4, 4), 256, 0, stream>>>(anchors, W1, b1, Gh);

    int hpb = (HG >= 2) ? 2 : 1;          // heads per main-block
    for (int h0 = 0; h0 < NH; h0 += HG) {
        hx_kernel<<<dim3(64, HG * 2), 256, 0, stream>>>(Xb, Wb, HXh, h0);
        main2_kernel<<<dim3(128, 2, HG / hpb), 256, 0, stream>>>(HXh, Gh, W2h, b2, out, h0, hpb);
    }
    hipMemcpyAsync(out + (size_t)NROWS * NA, anchors, (size_t)NA * FD * sizeof(float),
                   hipMemcpyDeviceToDevice, stream);
}